// Round 1
// baseline (1124.936 us; speedup 1.0000x reference)
//
#include <hip/hip_runtime.h>
#include <hip/hip_bf16.h>

typedef __bf16 bf16;
typedef __bf16 bf16x8 __attribute__((ext_vector_type(8)));
typedef float f32x4 __attribute__((ext_vector_type(4)));

#define DEV static __device__ __forceinline__

#define BB 2
#define NTOK 512
#define NATOM 16384
#define CT 384
#define CA 128
#define CP 16
#define CS 384
#define NQ 32
#define NK 128
#define NH 4
#define DH 32
#define NWIN 512
#define MTOT (BB*NATOM) /* 32768 */

DEV bf16x8 lds_ld8(const bf16* p){
  union { uint2 u[2]; bf16x8 v; } t;
  t.u[0] = *reinterpret_cast<const uint2*>(p);
  t.u[1] = *reinterpret_cast<const uint2*>(p + 4);
  return t.v;
}
DEV f32x4 mfma16(bf16x8 a, bf16x8 b, f32x4 c){
  return __builtin_amdgcn_mfma_f32_16x16x32_bf16(a, b, c, 0, 0, 0);
}
DEV float sigmoidf_(float x){ return 1.f/(1.f + __expf(-x)); }
DEV float red_sum64(float v){
  #pragma unroll
  for (int off = 1; off < 64; off <<= 1) v += __shfl_xor(v, off);
  return v;
}

// ---------------- GEMM building blocks: 64x64 tile, 256 threads ----------------
DEV void stage_A64(const bf16* __restrict__ Ag, int ldA, int m0, int k0,
                   bf16 (*As)[72], int tid){
  #pragma unroll
  for (int i = 0; i < 2; i++){
    int c = tid + i*256;            // 512 chunks of 8 bf16
    int row = c >> 3, off = (c & 7) * 8;
    uint4 d = *reinterpret_cast<const uint4*>(Ag + (size_t)(m0 + row)*ldA + k0 + off);
    uint2* dst = reinterpret_cast<uint2*>(&As[row][off]);
    dst[0] = make_uint2(d.x, d.y);
    dst[1] = make_uint2(d.z, d.w);
  }
}
DEV void stage_W64(const float* __restrict__ Wg, int ldW, int k0, int n0,
                   bf16 (*Ws)[72], int tid){
  #pragma unroll
  for (int i = 0; i < 4; i++){
    int c = tid + i*256;            // 1024 chunks of 4 f32
    int row = c >> 4, off = (c & 15) * 4;
    float4 d = *reinterpret_cast<const float4*>(Wg + (size_t)(k0 + row)*ldW + n0 + off);
    Ws[off+0][row] = (bf16)d.x;
    Ws[off+1][row] = (bf16)d.y;
    Ws[off+2][row] = (bf16)d.z;
    Ws[off+3][row] = (bf16)d.w;
  }
}
DEV void mma64(const bf16 (*As)[72], const bf16 (*Ws)[72], int wave, int lane,
               f32x4 acc[2][2]){
  int wm = (wave >> 1) * 32, wn = (wave & 1) * 32;
  int l16 = lane & 15, q8 = (lane >> 4) * 8;
  #pragma unroll
  for (int ks = 0; ks < 2; ks++){
    bf16x8 a0 = lds_ld8(&As[wm + l16][ks*32 + q8]);
    bf16x8 a1 = lds_ld8(&As[wm + 16 + l16][ks*32 + q8]);
    bf16x8 b0 = lds_ld8(&Ws[wn + l16][ks*32 + q8]);
    bf16x8 b1 = lds_ld8(&Ws[wn + 16 + l16][ks*32 + q8]);
    acc[0][0] = mfma16(a0, b0, acc[0][0]);
    acc[0][1] = mfma16(a0, b1, acc[0][1]);
    acc[1][0] = mfma16(a1, b0, acc[1][0]);
    acc[1][1] = mfma16(a1, b1, acc[1][1]);
  }
}

// ---------------- small prologue kernels ----------------
__global__ __launch_bounds__(128) void token_gemm(const float* __restrict__ a,
    const float* __restrict__ Wa, float* __restrict__ aW){
  __shared__ float arow[CT];
  int row = blockIdx.x;              // b*NTOK + t
  for (int j = threadIdx.x; j < CT; j += 128) arow[j] = a[(size_t)row*CT + j];
  __syncthreads();
  int c = threadIdx.x;
  float s = 0.f;
  for (int j = 0; j < CT; j++) s += arow[j] * Wa[(size_t)j*CA + c];
  aW[(size_t)row*CA + c] = s;
}

__global__ __launch_bounds__(256) void build_x0(const float* __restrict__ aW,
    const float* __restrict__ ef, const float* __restrict__ amask,
    const int* __restrict__ a2t, float* __restrict__ x,
    bf16* __restrict__ snc, float* __restrict__ tval){
  int ga = blockIdx.x * 4 + (threadIdx.x >> 6);
  int lane = threadIdx.x & 63;
  int b = ga >> 14;
  int tok = a2t[ga];
  float2 av = *reinterpret_cast<const float2*>(aW + ((size_t)(b*NTOK + tok))*CA + lane*2);
  float2 ev = *reinterpret_cast<const float2*>(ef + (size_t)ga*CA + lane*2);
  float m = amask[ga];
  *reinterpret_cast<float2*>(x + (size_t)ga*CA + lane*2) =
      make_float2((av.x + ev.x)*m, (av.y + ev.y)*m);
  // sn = LN of ef zero-padded to 384: tail channels collapse to t = -mu*rs
  float s = red_sum64(ev.x + ev.y);
  float mu = s * (1.f/384.f);
  float d0 = ev.x - mu, d1 = ev.y - mu;
  float vs = red_sum64(d0*d0 + d1*d1);
  float var = (vs + 256.f*mu*mu) * (1.f/384.f);
  float rs = rsqrtf(var + 1e-5f);
  bf16* sp = snc + (size_t)ga*CA + lane*2;
  sp[0] = (bf16)(d0*rs); sp[1] = (bf16)(d1*rs);
  if (lane == 0) tval[ga] = -mu*rs;
}

__global__ __launch_bounds__(128) void colsums(const float* ag, const float* ab,
    const float* sk, const float* tg, const float* tb, const float* tk,
    float* __restrict__ cs){
  int mat = blockIdx.x;              // 0..17
  int i = mat / 6, t = mat % 6;
  const float* base = t==0?ag : t==1?ab : t==2?sk : t==3?tg : t==4?tb : tk;
  const float* W = base + (size_t)i*CS*CA;
  int c = threadIdx.x;
  float s = 0.f;
  for (int k = CA; k < CS; k++) s += W[(size_t)k*CA + c];
  cs[(size_t)mat*CA + c] = s;
}

// ---------------- conditioning GEMMs (6 per block) ----------------
__global__ __launch_bounds__(256) void cond_gemm(const bf16* __restrict__ snc,
    const float* __restrict__ tval,
    const float* ag, const float* ab, const float* sk,
    const float* tg, const float* tb, const float* tk,
    const float* agb, const float* skb, const float* tgb, const float* tkb,
    const float* __restrict__ cs, bf16* __restrict__ cond){
  __shared__ bf16 As[64][72];
  __shared__ bf16 Ws[64][72];
  int tid = threadIdx.x, wave = tid >> 6, lane = tid & 63;
  int m0 = blockIdx.x * 64, n0 = blockIdx.y * 64;
  int type = blockIdx.z;
  const float* W; const float* bias; int sig;
  switch (type){
    case 0:  W = ag; bias = agb;     sig = 1; break;
    case 1:  W = ab; bias = nullptr; sig = 0; break;
    case 2:  W = sk; bias = skb;     sig = 1; break;
    case 3:  W = tg; bias = tgb;     sig = 1; break;
    case 4:  W = tb; bias = nullptr; sig = 0; break;
    default: W = tk; bias = tkb;     sig = 1; break;
  }
  f32x4 z = {0.f,0.f,0.f,0.f};
  f32x4 acc[2][2] = {{z,z},{z,z}};
  for (int kt = 0; kt < CA; kt += 64){
    stage_A64(snc, CA, m0, kt, As, tid);
    stage_W64(W, CA, kt, n0, Ws, tid);
    __syncthreads();
    mma64(As, Ws, wave, lane, acc);
    __syncthreads();
  }
  int wm = (wave >> 1)*32, wn = (wave & 1)*32, l16 = lane & 15, quad = lane >> 4;
  const float* csrow = cs + (size_t)type*CA;
  bf16* outp = cond + (size_t)type*MTOT*CA;
  #pragma unroll
  for (int mt = 0; mt < 2; mt++)
  #pragma unroll
  for (int nt = 0; nt < 2; nt++)
  #pragma unroll
  for (int r = 0; r < 4; r++){
    int m = m0 + wm + mt*16 + quad*4 + r;
    int n = n0 + wn + nt*16 + l16;
    float v = acc[mt][nt][r] + tval[m]*csrow[n];
    if (bias) v += bias[n];
    if (sig)  v = sigmoidf_(v);
    outp[(size_t)m*CA + n] = (bf16)v;
  }
}

// ---------------- AdaLN: out = g * LN(x) + b ----------------
__global__ __launch_bounds__(256) void adaln_kernel(const float* __restrict__ x,
    const bf16* __restrict__ g, const bf16* __restrict__ bt, bf16* __restrict__ outp){
  int ga = blockIdx.x * 4 + (threadIdx.x >> 6);
  int lane = threadIdx.x & 63;
  float2 xv = *reinterpret_cast<const float2*>(x + (size_t)ga*CA + lane*2);
  float s = red_sum64(xv.x + xv.y);
  float mu = s * (1.f/128.f);
  float d0 = xv.x - mu, d1 = xv.y - mu;
  float vs = red_sum64(d0*d0 + d1*d1);
  float rs = rsqrtf(vs*(1.f/128.f) + 1e-5f);
  const bf16* gp = g  + (size_t)ga*CA + lane*2;
  const bf16* bp = bt + (size_t)ga*CA + lane*2;
  bf16* op = outp + (size_t)ga*CA + lane*2;
  op[0] = (bf16)((float)gp[0]*(d0*rs) + (float)bp[0]);
  op[1] = (bf16)((float)gp[1]*(d1*rs) + (float)bp[1]);
}

// ---------------- QKVG projections ----------------
__global__ __launch_bounds__(256) void qkvg_gemm(const bf16* __restrict__ xa,
    const float* wq, const float* bq, const float* wk, const float* wv,
    const float* wg, bf16* __restrict__ outq){
  __shared__ bf16 As[64][72];
  __shared__ bf16 Ws[64][72];
  int tid = threadIdx.x, wave = tid >> 6, lane = tid & 63;
  int m0 = blockIdx.x * 64;
  int sel = blockIdx.y >> 1;
  int n0 = (blockIdx.y & 1) * 64;
  const float* W = sel==0 ? wq : sel==1 ? wk : sel==2 ? wv : wg;
  f32x4 z = {0.f,0.f,0.f,0.f};
  f32x4 acc[2][2] = {{z,z},{z,z}};
  for (int kt = 0; kt < CA; kt += 64){
    stage_A64(xa, CA, m0, kt, As, tid);
    stage_W64(W, CA, kt, n0, Ws, tid);
    __syncthreads();
    mma64(As, Ws, wave, lane, acc);
    __syncthreads();
  }
  int wm = (wave >> 1)*32, wn = (wave & 1)*32, l16 = lane & 15, quad = lane >> 4;
  #pragma unroll
  for (int mt = 0; mt < 2; mt++)
  #pragma unroll
  for (int nt = 0; nt < 2; nt++)
  #pragma unroll
  for (int r = 0; r < 4; r++){
    int m = m0 + wm + mt*16 + quad*4 + r;
    int n = n0 + wn + nt*16 + l16;
    float v = acc[mt][nt][r];
    if (sel == 0) v += bq[n];
    if (sel == 3) v = sigmoidf_(v);
    outq[(size_t)m*512 + sel*128 + n] = (bf16)v;
  }
}

// ---------------- windowed attention with pair bias ----------------
__global__ __launch_bounds__(256) void attn_kernel(const bf16* __restrict__ qkvg,
    const float* __restrict__ p_lm, const float* __restrict__ amask,
    const float* __restrict__ pgv, const float* __restrict__ pbv,
    const float* __restrict__ wpbv, bf16* __restrict__ go){
  __shared__ bf16 Qs[32][136];
  __shared__ bf16 Ks[128][136];   // reused as bias buffer, then P buffers
  __shared__ bf16 Vts[128][136];  // V transposed [d][key]
  __shared__ float kmask[128];
  int w = blockIdx.x, b = blockIdx.y;
  int tid = threadIdx.x;
  int wave = tid >> 6, lane = tid & 63, l16 = lane & 15, quad = lane >> 4;
  size_t abase = (size_t)b*NATOM + (size_t)w*NQ;
  int kstart = w*NQ + NQ/2 - NK/2;   // w*32 - 48
  if (tid < 128){
    int pos = kstart + tid;
    kmask[tid] = (pos >= 0 && pos < NATOM) ? amask[(size_t)b*NATOM + pos] : 0.f;
  }
  #pragma unroll
  for (int i = 0; i < 2; i++){      // Q: 32x128
    int c = tid + i*256;
    int row = c >> 4, off = (c & 15)*8;
    uint4 d = *reinterpret_cast<const uint4*>(qkvg + (abase + row)*512 + off);
    *reinterpret_cast<uint4*>(&Qs[row][off]) = d;
  }
  #pragma unroll
  for (int i = 0; i < 8; i++){      // K: 128x128
    int c = tid + i*256;
    int row = c >> 4, off = (c & 15)*8;
    int ka = kstart + row; ka = ka < 0 ? 0 : (ka > NATOM-1 ? NATOM-1 : ka);
    uint4 d = *reinterpret_cast<const uint4*>(qkvg + ((size_t)b*NATOM + ka)*512 + 128 + off);
    *reinterpret_cast<uint4*>(&Ks[row][off]) = d;
  }
  #pragma unroll
  for (int i = 0; i < 16; i++){     // V transposed
    int c = tid + i*256;
    int row = c >> 5, off = (c & 31)*4;   // row=key, off=channel
    int ka = kstart + row; ka = ka < 0 ? 0 : (ka > NATOM-1 ? NATOM-1 : ka);
    uint2 d = *reinterpret_cast<const uint2*>(qkvg + ((size_t)b*NATOM + ka)*512 + 256 + off);
    union { uint2 u; bf16 h[4]; } t; t.u = d;
    Vts[off+0][row] = t.h[0];
    Vts[off+1][row] = t.h[1];
    Vts[off+2][row] = t.h[2];
    Vts[off+3][row] = t.h[3];
  }
  __syncthreads();
  int h = wave;
  // QK^T per head
  f32x4 z4 = {0.f,0.f,0.f,0.f};
  f32x4 sacc[2][8];
  #pragma unroll
  for (int mt = 0; mt < 2; mt++)
    #pragma unroll
    for (int nt = 0; nt < 8; nt++) sacc[mt][nt] = z4;
  {
    bf16x8 bfr[8];
    #pragma unroll
    for (int nt = 0; nt < 8; nt++) bfr[nt] = lds_ld8(&Ks[nt*16 + l16][h*32 + quad*8]);
    #pragma unroll
    for (int mt = 0; mt < 2; mt++){
      bf16x8 a = lds_ld8(&Qs[mt*16 + l16][h*32 + quad*8]);
      #pragma unroll
      for (int nt = 0; nt < 8; nt++) sacc[mt][nt] = mfma16(a, bfr[nt], sacc[mt][nt]);
    }
  }
  __syncthreads();   // all waves done reading Ks -> reuse as bias buffer
  // bias = LN(p_lm; pg,pb) @ wpb, folded: rsig*(p.w_eff - mu*sum_w) + const
  f32x4 wj4[16]; f32x4 wsum4 = z4, cconst4 = z4;
  #pragma unroll
  for (int j = 0; j < 16; j++){
    f32x4 wp = { wpbv[j*4+0], wpbv[j*4+1], wpbv[j*4+2], wpbv[j*4+3] };
    wj4[j] = pgv[j] * wp;
    wsum4 += wj4[j];
    cconst4 += pbv[j] * wp;
  }
  size_t pbase = ((size_t)(b*NWIN + w)) * NQ * NK * CP;
  bf16* BiasBuf = &Ks[0][0];   // [q][k][h] flat, 16384 bf16
  {
    #pragma unroll 4
    for (int t = 0; t < 16; t++){
      int pid = t*64 + lane;           // 0..1023 = (q, kk)
      int q = pid >> 5;
      int k = wave*32 + (pid & 31);
      const float* pp = p_lm + pbase + ((size_t)q*NK + k)*CP;
      float4 p0 = *reinterpret_cast<const float4*>(pp);
      float4 p1 = *reinterpret_cast<const float4*>(pp + 4);
      float4 p2 = *reinterpret_cast<const float4*>(pp + 8);
      float4 p3 = *reinterpret_cast<const float4*>(pp + 12);
      float sm = p0.x+p0.y+p0.z+p0.w + p1.x+p1.y+p1.z+p1.w
               + p2.x+p2.y+p2.z+p2.w + p3.x+p3.y+p3.z+p3.w;
      float sq = p0.x*p0.x+p0.y*p0.y+p0.z*p0.z+p0.w*p0.w
               + p1.x*p1.x+p1.y*p1.y+p1.z*p1.z+p1.w*p1.w
               + p2.x*p2.x+p2.y*p2.y+p2.z*p2.z+p2.w*p2.w
               + p3.x*p3.x+p3.y*p3.y+p3.z*p3.z+p3.w*p3.w;
      f32x4 dw = z4;
      dw += p0.x*wj4[0];  dw += p0.y*wj4[1];  dw += p0.z*wj4[2];  dw += p0.w*wj4[3];
      dw += p1.x*wj4[4];  dw += p1.y*wj4[5];  dw += p1.z*wj4[6];  dw += p1.w*wj4[7];
      dw += p2.x*wj4[8];  dw += p2.y*wj4[9];  dw += p2.z*wj4[10]; dw += p2.w*wj4[11];
      dw += p3.x*wj4[12]; dw += p3.y*wj4[13]; dw += p3.z*wj4[14]; dw += p3.w*wj4[15];
      float mu = sm * (1.f/16.f);
      float var = fmaxf(sq*(1.f/16.f) - mu*mu, 0.f);
      float rsg = rsqrtf(var + 1e-5f);
      f32x4 bias4 = rsg*(dw - mu*wsum4) + cconst4;
      union { uint2 u; bf16 hh[4]; } tb;
      tb.hh[0] = (bf16)bias4.x; tb.hh[1] = (bf16)bias4.y;
      tb.hh[2] = (bf16)bias4.z; tb.hh[3] = (bf16)bias4.w;
      *reinterpret_cast<uint2*>(&BiasBuf[((size_t)q*NK + k)*4]) = tb.u;
    }
  }
  __syncthreads();
  // apply scale + bias + mask
  const float invs = 0.17677669529663689f;   // 1/sqrt(32)
  #pragma unroll
  for (int mt = 0; mt < 2; mt++)
  #pragma unroll
  for (int r = 0; r < 4; r++){
    int q = mt*16 + quad*4 + r;
    #pragma unroll
    for (int nt = 0; nt < 8; nt++){
      int k = nt*16 + l16;
      float biasv = (float)BiasBuf[((size_t)q*NK + k)*4 + h];
      float sv = sacc[mt][nt][r]*invs + biasv;
      sacc[mt][nt][r] = (kmask[k] > 0.f) ? sv : -1e9f;
    }
  }
  // softmax over k
  float rinv[2][4];
  #pragma unroll
  for (int mt = 0; mt < 2; mt++)
  #pragma unroll
  for (int r = 0; r < 4; r++){
    float mx = -3.0e38f;
    #pragma unroll
    for (int nt = 0; nt < 8; nt++) mx = fmaxf(mx, sacc[mt][nt][r]);
    #pragma unroll
    for (int off = 1; off < 16; off <<= 1) mx = fmaxf(mx, __shfl_xor(mx, off));
    float ss = 0.f;
    #pragma unroll
    for (int nt = 0; nt < 8; nt++){
      float e = __expf(sacc[mt][nt][r] - mx);
      sacc[mt][nt][r] = e; ss += e;
    }
    #pragma unroll
    for (int off = 1; off < 16; off <<= 1) ss += __shfl_xor(ss, off);
    rinv[mt][r] = 1.f/ss;
  }
  __syncthreads();   // everyone done reading BiasBuf -> reuse as P
  bf16 (*Ph)[136] = reinterpret_cast<bf16(*)[136]>(&Ks[h*32][0]);
  #pragma unroll
  for (int mt = 0; mt < 2; mt++)
  #pragma unroll
  for (int nt = 0; nt < 8; nt++)
  #pragma unroll
  for (int r = 0; r < 4; r++)
    Ph[mt*16 + quad*4 + r][nt*16 + l16] = (bf16)(sacc[mt][nt][r]*rinv[mt][r]);
  // PV (wave-private P, stable Vts: no barrier needed)
  f32x4 oacc[2][2] = {{z4,z4},{z4,z4}};
  #pragma unroll
  for (int kt = 0; kt < 4; kt++){
    bf16x8 a0 = lds_ld8(&Ph[l16][kt*32 + quad*8]);
    bf16x8 a1 = lds_ld8(&Ph[16 + l16][kt*32 + quad*8]);
    bf16x8 b0 = lds_ld8(&Vts[h*32 + l16][kt*32 + quad*8]);
    bf16x8 b1 = lds_ld8(&Vts[h*32 + 16 + l16][kt*32 + quad*8]);
    oacc[0][0] = mfma16(a0, b0, oacc[0][0]);
    oacc[0][1] = mfma16(a0, b1, oacc[0][1]);
    oacc[1][0] = mfma16(a1, b0, oacc[1][0]);
    oacc[1][1] = mfma16(a1, b1, oacc[1][1]);
  }
  #pragma unroll
  for (int mt = 0; mt < 2; mt++)
  #pragma unroll
  for (int nt = 0; nt < 2; nt++)
  #pragma unroll
  for (int r = 0; r < 4; r++){
    int q = mt*16 + quad*4 + r;
    int dcol = h*32 + nt*16 + l16;
    size_t arow = abase + q;
    float gate = (float)qkvg[arow*512 + 384 + dcol];
    go[arow*CA + dcol] = (bf16)(gate * oacc[mt][nt][r]);
  }
}

// ---------------- residual GEMM: x += gate * (A @ W) ----------------
template<int K>
__global__ __launch_bounds__(256) void resid_gemm(const bf16* __restrict__ Ain,
    const float* __restrict__ W, const bf16* __restrict__ gatec,
    float* __restrict__ x){
  __shared__ bf16 As[64][72];
  __shared__ bf16 Ws[64][72];
  int tid = threadIdx.x, wave = tid >> 6, lane = tid & 63;
  int m0 = blockIdx.x * 64, n0 = blockIdx.y * 64;
  f32x4 z = {0.f,0.f,0.f,0.f};
  f32x4 acc[2][2] = {{z,z},{z,z}};
  for (int kt = 0; kt < K; kt += 64){
    stage_A64(Ain, K, m0, kt, As, tid);
    stage_W64(W, CA, kt, n0, Ws, tid);
    __syncthreads();
    mma64(As, Ws, wave, lane, acc);
    __syncthreads();
  }
  int wm = (wave >> 1)*32, wn = (wave & 1)*32, l16 = lane & 15, quad = lane >> 4;
  #pragma unroll
  for (int mt = 0; mt < 2; mt++)
  #pragma unroll
  for (int nt = 0; nt < 2; nt++)
  #pragma unroll
  for (int r = 0; r < 4; r++){
    int m = m0 + wm + mt*16 + quad*4 + r;
    int n = n0 + wn + nt*16 + l16;
    size_t idx = (size_t)m*CA + n;
    x[idx] += (float)gatec[idx] * acc[mt][nt][r];
  }
}

// ---------------- SwiGLU transition first stage ----------------
__global__ __launch_bounds__(256) void t12_gemm(const bf16* __restrict__ xt,
    const float* __restrict__ w1, const float* __restrict__ w2,
    bf16* __restrict__ hsw){
  __shared__ bf16 As[64][72];
  __shared__ bf16 Ws[64][72];
  int tid = threadIdx.x, wave = tid >> 6, lane = tid & 63;
  int m0 = blockIdx.x * 64, n0 = blockIdx.y * 64;   // n0 in [0,256)
  f32x4 z = {0.f,0.f,0.f,0.f};
  f32x4 acc1[2][2] = {{z,z},{z,z}};
  f32x4 acc2[2][2] = {{z,z},{z,z}};
  for (int kt = 0; kt < CA; kt += 64){
    stage_A64(xt, CA, m0, kt, As, tid);
    stage_W64(w1, 2*CA, kt, n0, Ws, tid);
    __syncthreads();
    mma64(As, Ws, wave, lane, acc1);
    __syncthreads();
    stage_W64(w2, 2*CA, kt, n0, Ws, tid);
    __syncthreads();
    mma64(As, Ws, wave, lane, acc2);
    __syncthreads();
  }
  int wm = (wave >> 1)*32, wn = (wave & 1)*32, l16 = lane & 15, quad = lane >> 4;
  #pragma unroll
  for (int mt = 0; mt < 2; mt++)
  #pragma unroll
  for (int nt = 0; nt < 2; nt++)
  #pragma unroll
  for (int r = 0; r < 4; r++){
    int m = m0 + wm + mt*16 + quad*4 + r;
    int n = n0 + wn + nt*16 + l16;
    float v1 = acc1[mt][nt][r];
    float v2 = acc2[mt][nt][r];
    hsw[(size_t)m*(2*CA) + n] = (bf16)(v1*sigmoidf_(v1)*v2);
  }
}

// ---------------- final LN + projection to 3 ----------------
__global__ __launch_bounds__(256) void final_kernel(const float* __restrict__ x,
    const float* __restrict__ amask, const float* __restrict__ lg,
    const float* __restrict__ lb, const float* __restrict__ Wout,
    float* __restrict__ outp){
  int ga = blockIdx.x * 4 + (threadIdx.x >> 6);
  int lane = threadIdx.x & 63;
  float2 xv = *reinterpret_cast<const float2*>(x + (size_t)ga*CA + lane*2);
  float m = amask[ga];
  xv.x *= m; xv.y *= m;
  float s = red_sum64(xv.x + xv.y);
  float mu = s * (1.f/128.f);
  float d0 = xv.x - mu, d1 = xv.y - mu;
  float vs = red_sum64(d0*d0 + d1*d1);
  float rs = rsqrtf(vs*(1.f/128.f) + 1e-5f);
  int c = lane*2;
  float xn0 = d0*rs*lg[c]   + lb[c];
  float xn1 = d1*rs*lg[c+1] + lb[c+1];
  float p0 = xn0*Wout[c*3+0] + xn1*Wout[(c+1)*3+0];
  float p1 = xn0*Wout[c*3+1] + xn1*Wout[(c+1)*3+1];
  float p2 = xn0*Wout[c*3+2] + xn1*Wout[(c+1)*3+2];
  p0 = red_sum64(p0); p1 = red_sum64(p1); p2 = red_sum64(p2);
  if (lane == 0){
    outp[(size_t)ga*3 + 0] = p0;
    outp[(size_t)ga*3 + 1] = p1;
    outp[(size_t)ga*3 + 2] = p2;
  }
}

extern "C" void kernel_launch(void* const* d_in, const int* in_sizes, int n_in,
                              void* d_out, int out_size, void* d_ws, size_t ws_size,
                              hipStream_t stream){
  (void)in_sizes; (void)n_in; (void)out_size; (void)ws_size;
  const float* a     = (const float*)d_in[0];
  const float* ef    = (const float*)d_in[2];
  const float* p_lm  = (const float*)d_in[3];
  const float* amask = (const float*)d_in[4];
  const int*   a2t   = (const int*)d_in[5];
  const float* Wa    = (const float*)d_in[6];
  const float* lnq_g = (const float*)d_in[7];
  const float* lnq_b = (const float*)d_in[8];
  const float* Wout  = (const float*)d_in[9];
  const float* ag_w  = (const float*)d_in[10];
  const float* ag_b  = (const float*)d_in[11];
  const float* ab_w  = (const float*)d_in[12];
  const float* wq    = (const float*)d_in[13];
  const float* bq    = (const float*)d_in[14];
  const float* wk    = (const float*)d_in[15];
  const float* wv    = (const float*)d_in[16];
  const float* pg    = (const float*)d_in[17];
  const float* pb    = (const float*)d_in[18];
  const float* wpb   = (const float*)d_in[19];
  const float* wg    = (const float*)d_in[20];
  const float* wo    = (const float*)d_in[21];
  const float* sk_w  = (const float*)d_in[22];
  const float* sk_b  = (const float*)d_in[23];
  const float* tg_w  = (const float*)d_in[24];
  const float* tg_b  = (const float*)d_in[25];
  const float* tb_w  = (const float*)d_in[26];
  const float* wt1   = (const float*)d_in[27];
  const float* wt2   = (const float*)d_in[28];
  const float* wto   = (const float*)d_in[29];
  const float* tk_w  = (const float*)d_in[30];
  const float* tk_b  = (const float*)d_in[31];
  float* out = (float*)d_out;
  char* ws = (char*)d_ws;

  const size_t OFF_X    = 0;                       // 32768*128*4 = 16 MiB
  const size_t OFF_SNC  = OFF_X    + (size_t)MTOT*CA*4;
  const size_t OFF_TVAL = OFF_SNC  + (size_t)MTOT*CA*2;
  const size_t OFF_AW   = OFF_TVAL + (size_t)MTOT*4;
  const size_t OFF_CS   = OFF_AW   + (size_t)BB*NTOK*CA*4;
  const size_t OFF_COND = OFF_CS   + 18*CA*4 + 256;
  const size_t OFF_XA   = OFF_COND + (size_t)6*MTOT*CA*2;
  const size_t OFF_QKVG = OFF_XA   + (size_t)MTOT*CA*2;
  const size_t OFF_GO   = OFF_QKVG + (size_t)MTOT*512*2;

  float* x    = (float*)(ws + OFF_X);
  bf16*  snc  = (bf16*)(ws + OFF_SNC);
  float* tval = (float*)(ws + OFF_TVAL);
  float* aW   = (float*)(ws + OFF_AW);
  float* cs   = (float*)(ws + OFF_CS);
  bf16*  cond = (bf16*)(ws + OFF_COND);
  bf16*  xa   = (bf16*)(ws + OFF_XA);
  bf16*  qkvg = (bf16*)(ws + OFF_QKVG);
  bf16*  go   = (bf16*)(ws + OFF_GO);
  const size_t CSZ = (size_t)MTOT*CA;

  token_gemm<<<BB*NTOK, 128, 0, stream>>>(a, Wa, aW);
  build_x0<<<MTOT/4, 256, 0, stream>>>(aW, ef, amask, a2t, x, snc, tval);
  colsums<<<18, 128, 0, stream>>>(ag_w, ab_w, sk_w, tg_w, tb_w, tk_w, cs);

  for (int i = 0; i < 3; i++){
    size_t o384 = (size_t)i*CS*CA, o128 = (size_t)i*CA*CA, ob = (size_t)i*CA;
    cond_gemm<<<dim3(MTOT/64, 2, 6), 256, 0, stream>>>(snc, tval,
        ag_w + o384, ab_w + o384, sk_w + o384, tg_w + o384, tb_w + o384, tk_w + o384,
        ag_b + ob, sk_b + ob, tg_b + ob, tk_b + ob,
        cs + (size_t)i*6*CA, cond);
    adaln_kernel<<<MTOT/4, 256, 0, stream>>>(x, cond + 0*CSZ, cond + 1*CSZ, xa);
    qkvg_gemm<<<dim3(MTOT/64, 8), 256, 0, stream>>>(xa,
        wq + o128, bq + ob, wk + o128, wv + o128, wg + o128, qkvg);
    attn_kernel<<<dim3(NWIN, BB), 256, 0, stream>>>(qkvg, p_lm, amask,
        pg + (size_t)i*CP, pb + (size_t)i*CP, wpb + (size_t)i*CP*NH, go);
    resid_gemm<128><<<dim3(MTOT/64, 2), 256, 0, stream>>>(go, wo + o128,
        cond + 2*CSZ, x);
    adaln_kernel<<<MTOT/4, 256, 0, stream>>>(x, cond + 3*CSZ, cond + 4*CSZ, xa);
    t12_gemm<<<dim3(MTOT/64, 4), 256, 0, stream>>>(xa,
        wt1 + (size_t)i*CA*2*CA, wt2 + (size_t)i*CA*2*CA, qkvg /* hsw reuse */);
    resid_gemm<256><<<dim3(MTOT/64, 2), 256, 0, stream>>>(qkvg /* hsw */,
        wto + (size_t)i*2*CA*CA, cond + 5*CSZ, x);
  }
  final_kernel<<<MTOT/4, 256, 0, stream>>>(x, amask, lnq_g, lnq_b, Wout, out);
}